// Round 2
// baseline (105.214 us; speedup 1.0000x reference)
//
#include <hip/hip_runtime.h>
#include <math.h>

// HDCFactMemory: out = x + r_gate * sign(memory) * sign(x) * sign(role_read)
//   memory = cumsum_t( sign(x)*sign(role_write)*w_gate )
// Factor sign(role_write[d]) out of the cumsum (exact in FP):
//   out = x + r_gate[b,t] * K[d] * sign(S[b,t,d]) * sign(x[b,t,d])
//   K[d] = sign(role_write[d])*sign(role_read[d])
//   S[b,t,d] = sum_{t'<=t} sign(x[b,t',d]) * w_gate[b,t']
// ALL sign-determining arithmetic (gates, scan) in f64 to match the np-f64
// reference: sign flips of S near 0 were the R1 failure (absmax 1.22 = 2*r_gate).

#define T_LEN 4096
#define D_LEN 4096
#define NC 64              // number of T-chunks
#define TC (T_LEN / NC)    // 64 timesteps per chunk
#define D4 (D_LEN / 4)     // 1024 float4 per row

__device__ __forceinline__ float fsgn(float v) {
    return (v > 0.f) ? 1.f : ((v < 0.f) ? -1.f : 0.f);
}
__device__ __forceinline__ double dsgn(double v) {
    return (v > 0.) ? 1. : ((v < 0.) ? -1. : 0.);
}

// ---- Kernel 1: per-row gates (two f64 dot products over D, then sigmoid) ----
__global__ __launch_bounds__(256) void gates_kernel(
    const float* __restrict__ x,
    const float* __restrict__ wg_w, const float* __restrict__ wg_b,
    const float* __restrict__ rg_w, const float* __restrict__ rg_b,
    double* __restrict__ wgate, double* __restrict__ rgate)
{
    const int row = blockIdx.x;                  // b*T + t
    const float4* xr = (const float4*)(x + (size_t)row * D_LEN);
    const float4* w4 = (const float4*)wg_w;
    const float4* r4 = (const float4*)rg_w;

    double dw = 0., dr = 0.;
    for (int i = threadIdx.x; i < D4; i += 256) {
        float4 v = xr[i];
        float4 a = w4[i];
        float4 b = r4[i];
        dw += (double)v.x * a.x + (double)v.y * a.y
            + (double)v.z * a.z + (double)v.w * a.w;
        dr += (double)v.x * b.x + (double)v.y * b.y
            + (double)v.z * b.z + (double)v.w * b.w;
    }
    for (int off = 32; off > 0; off >>= 1) {
        dw += __shfl_down(dw, off);
        dr += __shfl_down(dr, off);
    }
    __shared__ double sdw[4], sdr[4];
    const int wid = threadIdx.x >> 6;
    if ((threadIdx.x & 63) == 0) { sdw[wid] = dw; sdr[wid] = dr; }
    __syncthreads();
    if (threadIdx.x == 0) {
        double zw = sdw[0] + sdw[1] + sdw[2] + sdw[3] + (double)wg_b[0];
        double zr = sdr[0] + sdr[1] + sdr[2] + sdr[3] + (double)rg_b[0];
        wgate[row] = 1. / (1. + exp(-zw));
        rgate[row] = 1. / (1. + exp(-zr));
    }
}

// ---- Kernel 2: per-chunk f64 partial sums of sign(x)*w_gate over t ----
__global__ __launch_bounds__(256) void partial_kernel(
    const float* __restrict__ x,
    const double* __restrict__ wgate,
    double* __restrict__ partial)
{
    const int b = blockIdx.z;
    const int c = blockIdx.y;
    const int d4 = blockIdx.x * 256 + threadIdx.x;   // float4 column index

    __shared__ double wsm[TC];
    if (threadIdx.x < TC)
        wsm[threadIdx.x] = wgate[b * T_LEN + c * TC + threadIdx.x];
    __syncthreads();

    const float4* x4 = (const float4*)x;
    size_t base = ((size_t)b * T_LEN + (size_t)c * TC) * D4 + d4;

    double ax = 0., ay = 0., az = 0., aw = 0.;
    #pragma unroll 4
    for (int i = 0; i < TC; ++i) {
        float4 v = x4[base + (size_t)i * D4];
        double w = wsm[i];
        ax += (double)fsgn(v.x) * w;
        ay += (double)fsgn(v.y) * w;
        az += (double)fsgn(v.z) * w;
        aw += (double)fsgn(v.w) * w;
    }
    double* p = partial + (((size_t)(b * NC + c)) * D4 + d4) * 4;
    p[0] = ax; p[1] = ay; p[2] = az; p[3] = aw;
}

// ---- Kernel 3: prefix offset + in-chunk sequential f64 scan + output ----
__global__ __launch_bounds__(256) void final_kernel(
    const float* __restrict__ x,
    const double* __restrict__ wgate, const double* __restrict__ rgate,
    const float* __restrict__ role_w, const float* __restrict__ role_r,
    const double* __restrict__ partial,
    float* __restrict__ out)
{
    const int b = blockIdx.z;
    const int c = blockIdx.y;
    const int d4 = blockIdx.x * 256 + threadIdx.x;

    __shared__ double wsm[TC], rsm[TC];
    if (threadIdx.x < TC) {
        wsm[threadIdx.x] = wgate[b * T_LEN + c * TC + threadIdx.x];
        rsm[threadIdx.x] = rgate[b * T_LEN + c * TC + threadIdx.x];
    }
    __syncthreads();

    float4 rw = ((const float4*)role_w)[d4];
    float4 rr = ((const float4*)role_r)[d4];
    const double kx = (double)(fsgn(rw.x) * fsgn(rr.x));
    const double ky = (double)(fsgn(rw.y) * fsgn(rr.y));
    const double kz = (double)(fsgn(rw.z) * fsgn(rr.z));
    const double kw = (double)(fsgn(rw.w) * fsgn(rr.w));

    // exclusive prefix over earlier chunks, ascending order
    double ax = 0., ay = 0., az = 0., aw = 0.;
    for (int c2 = 0; c2 < c; ++c2) {
        const double* p = partial + (((size_t)(b * NC + c2)) * D4 + d4) * 4;
        ax += p[0]; ay += p[1]; az += p[2]; aw += p[3];
    }

    const float4* x4 = (const float4*)x;
    float4* o4 = (float4*)out;
    size_t base = ((size_t)b * T_LEN + (size_t)c * TC) * D4 + d4;

    #pragma unroll 4
    for (int i = 0; i < TC; ++i) {
        float4 v = x4[base + (size_t)i * D4];
        double w = wsm[i];
        double r = rsm[i];
        double sx = (double)fsgn(v.x), sy = (double)fsgn(v.y);
        double sz = (double)fsgn(v.z), sw2 = (double)fsgn(v.w);
        ax += sx * w; ay += sy * w; az += sz * w; aw += sw2 * w;
        float4 o;
        o.x = (float)((double)v.x + r * kx * dsgn(ax) * sx);
        o.y = (float)((double)v.y + r * ky * dsgn(ay) * sy);
        o.z = (float)((double)v.z + r * kz * dsgn(az) * sz);
        o.w = (float)((double)v.w + r * kw * dsgn(aw) * sw2);
        o4[base + (size_t)i * D4] = o;
    }
}

extern "C" void kernel_launch(void* const* d_in, const int* in_sizes, int n_in,
                              void* d_out, int out_size, void* d_ws, size_t ws_size,
                              hipStream_t stream) {
    const float* x      = (const float*)d_in[0];
    const float* role_w = (const float*)d_in[1];
    const float* role_r = (const float*)d_in[2];
    const float* wg_w   = (const float*)d_in[3];
    const float* wg_b   = (const float*)d_in[4];
    const float* rg_w   = (const float*)d_in[5];
    const float* rg_b   = (const float*)d_in[6];
    float* out = (float*)d_out;

    const int B = in_sizes[0] / (T_LEN * D_LEN);   // = 2
    const int BT = B * T_LEN;

    // workspace layout (all f64): wgate[BT], rgate[BT], partial[B*NC*D]
    double* wgate   = (double*)d_ws;
    double* rgate   = wgate + BT;
    double* partial = rgate + BT;   // ~4.2 MB total

    gates_kernel<<<BT, 256, 0, stream>>>(x, wg_w, wg_b, rg_w, rg_b, wgate, rgate);

    dim3 grid(D4 / 256, NC, B);   // (4, 64, 2)
    partial_kernel<<<grid, 256, 0, stream>>>(x, wgate, partial);
    final_kernel<<<grid, 256, 0, stream>>>(x, wgate, rgate, role_w, role_r,
                                           partial, out);
}